// Round 11
// baseline (191.858 us; speedup 1.0000x reference)
//
#include <hip/hip_runtime.h>

// SAGE layer: out = relu(x @ W_self + (segment_sum(x[src], dst)/max(deg,1)) @ W_neigh + b)
//
// R10: scanA dispatch eliminated via fixed-stride bucket regions (pay2d[b][PCAP]).
//   1. k_conv:  x->bf16 + W->bf16^T; blocks < nchunk also histogram their 4096-edge chunk
//   2. k_place: block c computes its own pref[b]=sum_{c'<c} cnt[c'][b] (L2-hot 0.5MB),
//               places edges at pay2d[b*PCAP + pref[b] + rank]; last block writes btot
//   3. k_csr:   per-block LDS scan of btot -> global offsets; exact per-row CSR + row_start
//   4. k_aggregate: wave per dst row; 16 lanes/edge ushort4 gathers; shfl_xor reduce -> hb
//   5. k_gemm_mfma: A=[xb|hb] K=128, W from WtG, bias+relu (proven layout)
// R8 lesson kept: gather stays wave-per-row standalone. Zero global atomics.
// Fallback (small ws): R0 scatter + shfl gemm.

constexpr int F = 64;
constexpr int BROWS = 256;   // dst rows per bucket
constexpr int MAXNB = 512;   // max buckets (num_dst <= 131072)
constexpr int CHP = 4096;    // edges per chunk
constexpr int PCAP = 8192;   // slots per bucket region (3.2x mean load -> no overflow)
constexpr int LDK = 136;     // 128 + 8 pad (bf16 elems)

typedef __attribute__((ext_vector_type(8))) short short8;
typedef __attribute__((ext_vector_type(4))) float float4v;

__device__ inline unsigned short f2bf(float f) {
    union { float f; unsigned u; } c; c.f = f;
    unsigned u = c.u;
    return (unsigned short)((u + 0x7FFFu + ((u >> 16) & 1u)) >> 16);  // RNE
}
__device__ inline float bf2f(unsigned short h) {
    union { unsigned u; float f; } c; c.u = (unsigned)h << 16;
    return c.f;
}

// ---------------- 1. x->bf16 + W->bf16^T + per-chunk bucket counts ----------------
__global__ __launch_bounds__(256) void k_conv(const float* __restrict__ x,
                                              const float* __restrict__ Ws,
                                              const float* __restrict__ Wn,
                                              unsigned short* __restrict__ xb,
                                              unsigned short* __restrict__ WtG,
                                              const int* __restrict__ dst,
                                              int* __restrict__ cnt,
                                              long n4, int n_edges, int nchunk) {
    __shared__ int hist[MAXNB];
    int t = threadIdx.x;
    long tid = (long)blockIdx.x * 256 + t;
    // W -> bf16 transposed
    if (tid < 2 * F * F) {
        int i = (int)tid;
        int n = i & 63, k = i >> 6;
        float v = (k < 64) ? Ws[k * 64 + n] : Wn[(k - 64) * 64 + n];
        WtG[n * 128 + k] = f2bf(v);
    }
    // chunk histogram (blocks < nchunk)
    int c = blockIdx.x;
    if (c < nchunk) {
        for (int i = t; i < MAXNB; i += 256) hist[i] = 0;
        __syncthreads();
        int e0 = c * CHP, e1 = min(e0 + CHP, n_edges);
        for (int e = e0 + t; e < e1; e += 256) atomicAdd(&hist[dst[e] >> 8], 1);
        __syncthreads();
        for (int i = t; i < MAXNB; i += 256) cnt[(long)c * MAXNB + i] = hist[i];
    }
    // x -> bf16
    for (long i = tid; i < n4; i += (long)gridDim.x * 256) {
        float4 v = ((const float4*)x)[i];
        ushort4 o;
        o.x = f2bf(v.x); o.y = f2bf(v.y); o.z = f2bf(v.z); o.w = f2bf(v.w);
        ((ushort4*)xb)[i] = o;
    }
}

// ---------------- 2. place edges into fixed-stride bucket regions ----------------
__global__ __launch_bounds__(512) void k_place(const int* __restrict__ src,
                                               const int* __restrict__ dst,
                                               const int* __restrict__ cnt,
                                               unsigned* __restrict__ pay2d,
                                               int* __restrict__ btot,
                                               int n_edges, int nchunk) {
    __shared__ int pref[MAXNB];
    __shared__ int lcur[MAXNB];
    int t = threadIdx.x;       // t in [0,512) == bucket index (MAXNB == 512)
    int c = blockIdx.x;
    int p = 0;
    for (int cc = 0; cc < c; ++cc) p += cnt[(long)cc * MAXNB + t];
    pref[t] = p;
    lcur[t] = 0;
    if (c == nchunk - 1) btot[t] = p + cnt[(long)c * MAXNB + t];
    __syncthreads();
    int e0 = c * CHP, e1 = min(e0 + CHP, n_edges);
    for (int e = e0 + t; e < e1; e += 512) {
        int d = dst[e];
        int b = d >> 8;
        int rank = atomicAdd(&lcur[b], 1);
        pay2d[(long)b * PCAP + pref[b] + rank] = ((unsigned)src[e] << 8) | (unsigned)(d & 255);
    }
}

// shared helper: 512-wide exclusive scan of btot into sbst[0..MAXNB], total at sbst[MAXNB]
__device__ inline void scan_btot(const int* __restrict__ btot, int* sbst, int t) {
    int v = btot[t];
    sbst[t] = v;
    __syncthreads();
    for (int off = 1; off < MAXNB; off <<= 1) {
        int tv = (t >= off) ? sbst[t - off] : 0;
        __syncthreads();
        sbst[t] += tv;
        __syncthreads();
    }
    int incl = sbst[t];
    __syncthreads();
    sbst[t] = incl - v;           // exclusive
    if (t == MAXNB - 1) sbst[MAXNB] = incl;
    __syncthreads();
}

// ---------------- 3. per-bucket exact CSR ----------------
__global__ __launch_bounds__(512) void k_csr(const unsigned* __restrict__ pay2d,
                                             const int* __restrict__ btot,
                                             int* __restrict__ row_start,
                                             int* __restrict__ csr,
                                             int num_dst, int n_edges, int nb) {
    __shared__ int sbst[MAXNB + 1];
    __shared__ int hist[BROWS];
    __shared__ int scn[BROWS];
    int t = threadIdx.x;
    scan_btot(btot, sbst, t);
    int b = blockIdx.x;
    int s0 = sbst[b];
    int bt = sbst[b + 1] - s0;
    const unsigned* bp = &pay2d[(long)b * PCAP];
    if (t < BROWS) hist[t] = 0;
    __syncthreads();
    for (int i = t; i < bt; i += 512) atomicAdd(&hist[bp[i] & 255], 1);
    __syncthreads();
    int v = 0;
    if (t < BROWS) { v = hist[t]; scn[t] = v; }
    __syncthreads();
    for (int off = 1; off < BROWS; off <<= 1) {
        int tv = 0;
        if (t < BROWS && t >= off) tv = scn[t - off];
        __syncthreads();
        if (t < BROWS) scn[t] += tv;
        __syncthreads();
    }
    int r0 = b * BROWS;
    if (t < BROWS) {
        int excl = scn[t] - v;
        if (r0 + t < num_dst) row_start[r0 + t] = s0 + excl;
        hist[t] = excl;   // reuse as cursor
    }
    if (b == nb - 1 && t == 0) row_start[num_dst] = n_edges;
    __syncthreads();
    for (int i = t; i < bt; i += 512) {
        unsigned p = bp[i];
        int pos = atomicAdd(&hist[p & 255], 1);
        csr[s0 + pos] = (int)(p >> 8);
    }
}

// ---------------- 4. aggregate: wave per row, 16 lanes/edge ushort4 ----------------
__global__ __launch_bounds__(256) void k_aggregate(const unsigned short* __restrict__ xb,
                                                   const int* __restrict__ row_start,
                                                   const int* __restrict__ csr,
                                                   unsigned short* __restrict__ hb, int num_dst) {
    int lane = threadIdx.x & 63;
    int r = (blockIdx.x * 256 + threadIdx.x) >> 6;
    if (r >= num_dst) return;
    int g = lane >> 4;          // edge slot within group of 4
    int c4 = (lane & 15) * 4;   // feature quad
    int s0 = row_start[r], s1 = row_start[r + 1];
    int rem = s1 - s0;
    float4 accA = make_float4(0.f, 0.f, 0.f, 0.f);
    float4 accB = make_float4(0.f, 0.f, 0.f, 0.f);
    for (int base = 0; base < rem; base += 64) {
        int sid = (base + lane < rem) ? csr[s0 + base + lane] : 0;
        int n = min(64, rem - base);
        int i = 0;
        for (; i + 7 < n; i += 8) {
            int e0 = __shfl(sid, i + g);
            int e1 = __shfl(sid, i + 4 + g);
            ushort4 u0 = *(const ushort4*)&xb[(long)e0 * F + c4];
            ushort4 u1 = *(const ushort4*)&xb[(long)e1 * F + c4];
            accA.x += bf2f(u0.x); accA.y += bf2f(u0.y); accA.z += bf2f(u0.z); accA.w += bf2f(u0.w);
            accB.x += bf2f(u1.x); accB.y += bf2f(u1.y); accB.z += bf2f(u1.z); accB.w += bf2f(u1.w);
        }
        for (; i < n; i += 4) {
            int eslot = i + g;
            int e = __shfl(sid, eslot);
            if (eslot < n) {
                ushort4 u = *(const ushort4*)&xb[(long)e * F + c4];
                accA.x += bf2f(u.x); accA.y += bf2f(u.y); accA.z += bf2f(u.z); accA.w += bf2f(u.w);
            }
        }
    }
    float4 acc;
    acc.x = accA.x + accB.x; acc.y = accA.y + accB.y;
    acc.z = accA.z + accB.z; acc.w = accA.w + accB.w;
    acc.x += __shfl_xor(acc.x, 16); acc.y += __shfl_xor(acc.y, 16);
    acc.z += __shfl_xor(acc.z, 16); acc.w += __shfl_xor(acc.w, 16);
    acc.x += __shfl_xor(acc.x, 32); acc.y += __shfl_xor(acc.y, 32);
    acc.z += __shfl_xor(acc.z, 32); acc.w += __shfl_xor(acc.w, 32);
    if (lane < 16) {
        float inv = 1.0f / fmaxf((float)rem, 1.0f);
        ushort4 o;
        o.x = f2bf(acc.x * inv); o.y = f2bf(acc.y * inv);
        o.z = f2bf(acc.z * inv); o.w = f2bf(acc.w * inv);
        *(ushort4*)&hb[(long)r * F + c4] = o;
    }
}

// ---------------- 5. fused dual-GEMM, bf16 MFMA ----------------
__global__ __launch_bounds__(256) void k_gemm_mfma(
    const unsigned short* __restrict__ xb, const unsigned short* __restrict__ hb,
    const unsigned short* __restrict__ WtG,   // [n][k=0..127] bf16, pre-transposed
    const float* __restrict__ b, float* __restrict__ out, int num_dst)
{
    __shared__ __align__(16) unsigned short Atile[64 * LDK];
    __shared__ __align__(16) unsigned short Wt[64 * LDK];
    int t = threadIdx.x;
    int row0 = blockIdx.x * 64;

    for (int i = t; i < 64 * 16; i += 256) {
        int r = i >> 4, s = i & 15;
        *(short8*)&Wt[r * LDK + s * 8] = *(const short8*)&WtG[r * 128 + s * 8];
        int g = row0 + r;
        short8 v = {0, 0, 0, 0, 0, 0, 0, 0};
        if (g < num_dst)
            v = (s < 8) ? *(const short8*)&xb[(long)g * F + s * 8]
                        : *(const short8*)&hb[(long)g * F + (s - 8) * 8];
        *(short8*)&Atile[r * LDK + s * 8] = v;
    }
    __syncthreads();

    int lane = t & 63;
    int wave = t >> 6;
    int m = lane & 15;
    int quad = lane >> 4;
    const unsigned short* arow = &Atile[(wave * 16 + m) * LDK + quad * 8];

    float4v acc[4];
#pragma unroll
    for (int nt = 0; nt < 4; ++nt) acc[nt] = (float4v){0.f, 0.f, 0.f, 0.f};

#pragma unroll
    for (int kb = 0; kb < 4; ++kb) {
        short8 a = *(const short8*)(arow + kb * 32);
#pragma unroll
        for (int nt = 0; nt < 4; ++nt) {
            short8 bf = *(const short8*)&Wt[(nt * 16 + m) * LDK + quad * 8 + kb * 32];
            acc[nt] = __builtin_amdgcn_mfma_f32_16x16x32_bf16(a, bf, acc[nt], 0, 0, 0);
        }
    }

    int gr_base = row0 + wave * 16 + quad * 4;
#pragma unroll
    for (int nt = 0; nt < 4; ++nt) {
        int col = nt * 16 + m;
        float bias = b[col];
#pragma unroll
        for (int rg = 0; rg < 4; ++rg) {
            int g = gr_base + rg;
            if (g < num_dst) out[(long)g * F + col] = fmaxf(acc[nt][rg] + bias, 0.0f);
        }
    }
}

// ---------------- fallback (R0, proven) ----------------
__global__ __launch_bounds__(256) void k_scatter(const float* __restrict__ x, const int* __restrict__ src,
                                                 const int* __restrict__ dst, float* __restrict__ summed,
                                                 float* __restrict__ degf, int n_edges) {
    long tid = (long)blockIdx.x * 256 + threadIdx.x;
    int e = (int)(tid >> 6);
    if (e >= n_edges) return;
    int f = threadIdx.x & 63;
    atomicAdd(&summed[(long)dst[e] * F + f], x[(long)src[e] * F + f]);
    if (f == 0) atomicAdd(&degf[dst[e]], 1.0f);
}

__global__ __launch_bounds__(256) void k_gemm_shfl(
    const float* __restrict__ x, const float* __restrict__ Ws, const float* __restrict__ Wn,
    const float* __restrict__ b, const float* __restrict__ degf, float* inout, int num_dst)
{
    __shared__ float Wl[2 * F * F];
    for (int i = threadIdx.x; i < F * F; i += 256) { Wl[i] = Ws[i]; Wl[F * F + i] = Wn[i]; }
    __syncthreads();
    int lane = threadIdx.x & 63;
    int r = (blockIdx.x * 256 + threadIdx.x) >> 6;
    if (r >= num_dst) return;
    float xv = x[(long)r * F + lane];
    float hv = inout[(long)r * F + lane] / fmaxf(degf[r], 1.0f);
    float acc = b[lane];
#pragma unroll
    for (int k = 0; k < F; ++k) {
        acc += __shfl(xv, k) * Wl[k * F + lane];
        acc += __shfl(hv, k) * Wl[(F + k) * F + lane];
    }
    inout[(long)r * F + lane] = fmaxf(acc, 0.0f);
}

// ---------------- launch ----------------
extern "C" void kernel_launch(void* const* d_in, const int* in_sizes, int n_in,
                              void* d_out, int out_size, void* d_ws, size_t ws_size,
                              hipStream_t stream) {
    const float* x  = (const float*)d_in[0];
    const float* Ws = (const float*)d_in[1];
    const float* Wn = (const float*)d_in[2];
    const float* b  = (const float*)d_in[3];
    const int* src  = (const int*)d_in[4];
    const int* dst  = (const int*)d_in[5];
    int n_edges = in_sizes[4];
    int num_dst = out_size / F;
    float* out = (float*)d_out;

    int nchunk = (n_edges + CHP - 1) / CHP;
    int nb = (num_dst + BROWS - 1) / BROWS;

    char* ws = (char*)d_ws;
    size_t off = 0;
    auto alloc = [&](size_t bytes) { char* p = ws + off; off = (off + bytes + 255) & ~(size_t)255; return p; };
    unsigned short* xb  = (unsigned short*)alloc((size_t)num_dst * F * 2);
    unsigned short* hb  = (unsigned short*)alloc((size_t)num_dst * F * 2);
    unsigned* pay2d     = (unsigned*)alloc((size_t)MAXNB * PCAP * 4);
    int* csr            = (int*)alloc((size_t)n_edges * 4);
    int* row_start      = (int*)alloc((size_t)(num_dst + 1) * 4);
    unsigned short* WtG = (unsigned short*)alloc(2 * F * F * 2);
    int* cnt            = (int*)alloc((size_t)nchunk * MAXNB * 4);
    int* btot           = (int*)alloc(MAXNB * 4);
    // PCAP must comfortably exceed max bucket load (mean = n_edges*BROWS/num_dst)
    long mean_load = (num_dst > 0) ? ((long)n_edges * BROWS) / num_dst : 0;
    bool big_ws = (off <= ws_size) && (nb <= MAXNB) && (mean_load * 2 < PCAP);

    if (big_ws) {
        long n4 = (long)num_dst * F / 4;
        int convgrid = max(2048, nchunk);
        k_conv<<<convgrid, 256, 0, stream>>>(x, Ws, Wn, xb, WtG, dst, cnt, n4, n_edges, nchunk);
        k_place<<<nchunk, 512, 0, stream>>>(src, dst, cnt, pay2d, btot, n_edges, nchunk);
        k_csr<<<nb, 512, 0, stream>>>(pay2d, btot, row_start, csr, num_dst, n_edges, nb);
        k_aggregate<<<(num_dst + 3) / 4, 256, 0, stream>>>(xb, row_start, csr, hb, num_dst);
        k_gemm_mfma<<<(num_dst + 63) / 64, 256, 0, stream>>>(xb, hb, WtG, b, out, num_dst);
    } else {
        float* degf = (float*)d_ws;
        (void)hipMemsetAsync(d_out, 0, (size_t)out_size * sizeof(float), stream);
        (void)hipMemsetAsync(degf, 0, (size_t)num_dst * sizeof(float), stream);
        long tt = (long)n_edges * 64;
        k_scatter<<<(int)((tt + 255) / 256), 256, 0, stream>>>(x, src, dst, out, degf, n_edges);
        k_gemm_shfl<<<(num_dst + 3) / 4, 256, 0, stream>>>(x, Ws, Wn, b, degf, out, num_dst);
    }
}

// Round 12
// 167.063 us; speedup vs baseline: 1.1484x; 1.1484x over previous
//
#include <hip/hip_runtime.h>

// SAGE layer: out = relu(x @ W_self + (segment_sum(x[src], dst)/max(deg,1)) @ W_neigh + b)
//
// R11 = R9 structure (best: 167us) + 16B-per-lane aggregate gather.
// Failed-experiment log (do not repeat):
//   R4: LDS float atomicAdd = CAS loops -> 448us.  R6: 1-block serial scan -> 121us.
//   R8: gather fused into GEMM blocks (TLP/16) -> 70us kernel.
//   R10: per-block O(c) serial prefix + fixed-stride regions -> k_place 44.5us.
// Pipeline (6 dispatches, zero global atomics, no memsets on main path):
//   1. k_conv:  x->bf16 + W->bf16^T; blocks < nchunk also histogram their 4096-edge chunk
//   2. k_scanA: wave per bucket, parallel column scan of cnt -> per-chunk bases + btot
//   3. k_place: per-block LDS scan of btot -> bstart; place edges bucket-contiguously (pay)
//   4. k_csr:   per-block LDS scan of btot -> bstart; exact per-row CSR + row_start
//   5. k_aggregate: wave per dst row; 8 lanes/edge short8 (16B) gathers; shfl_xor reduce -> hb
//   6. k_gemm_mfma: A=[xb|hb] K=128, W from WtG, bias+relu (proven layout)
// Fallback (small ws): R0 scatter + shfl gemm.

constexpr int F = 64;
constexpr int BROWS = 256;   // dst rows per bucket
constexpr int MAXNB = 512;   // max buckets (num_dst <= 131072)
constexpr int CHP = 4096;    // edges per chunk
constexpr int LDK = 136;     // 128 + 8 pad (bf16 elems)

typedef __attribute__((ext_vector_type(8))) short short8;
typedef __attribute__((ext_vector_type(4))) float float4v;

__device__ inline unsigned short f2bf(float f) {
    union { float f; unsigned u; } c; c.f = f;
    unsigned u = c.u;
    return (unsigned short)((u + 0x7FFFu + ((u >> 16) & 1u)) >> 16);  // RNE
}
__device__ inline float bf2f(unsigned short h) {
    union { unsigned u; float f; } c; c.u = (unsigned)h << 16;
    return c.f;
}

// ---------------- 1. x->bf16 + W->bf16^T + per-chunk bucket counts ----------------
__global__ __launch_bounds__(256) void k_conv(const float* __restrict__ x,
                                              const float* __restrict__ Ws,
                                              const float* __restrict__ Wn,
                                              unsigned short* __restrict__ xb,
                                              unsigned short* __restrict__ WtG,
                                              const int* __restrict__ dst,
                                              int* __restrict__ cnt,
                                              long n4, int n_edges, int nchunk) {
    __shared__ int hist[MAXNB];
    int t = threadIdx.x;
    long tid = (long)blockIdx.x * 256 + t;
    // W -> bf16 transposed
    if (tid < 2 * F * F) {
        int i = (int)tid;
        int n = i & 63, k = i >> 6;
        float v = (k < 64) ? Ws[k * 64 + n] : Wn[(k - 64) * 64 + n];
        WtG[n * 128 + k] = f2bf(v);
    }
    // chunk histogram (blocks < nchunk)
    int c = blockIdx.x;
    if (c < nchunk) {
        for (int i = t; i < MAXNB; i += 256) hist[i] = 0;
        __syncthreads();
        int e0 = c * CHP, e1 = min(e0 + CHP, n_edges);
        for (int e = e0 + t; e < e1; e += 256) atomicAdd(&hist[dst[e] >> 8], 1);
        __syncthreads();
        for (int i = t; i < MAXNB; i += 256) cnt[(long)c * MAXNB + i] = hist[i];
    }
    // x -> bf16
    for (long i = tid; i < n4; i += (long)gridDim.x * 256) {
        float4 v = ((const float4*)x)[i];
        ushort4 o;
        o.x = f2bf(v.x); o.y = f2bf(v.y); o.z = f2bf(v.z); o.w = f2bf(v.w);
        ((ushort4*)xb)[i] = o;
    }
}

// ---------------- 2. parallel column scan: wave per bucket ----------------
__global__ __launch_bounds__(512) void k_scanA(int* __restrict__ cnt,   // in-place -> pref
                                               int* __restrict__ btot, int nchunk) {
    int b = (blockIdx.x * 512 + threadIdx.x) >> 6;   // bucket = global wave id
    int lane = threadIdx.x & 63;
    if (b >= MAXNB) return;
    int per = (nchunk + 63) / 64;                    // chunks per lane (<=16 for nchunk<=1024)
    int c0 = lane * per;
    int vals[16];
    int lsum = 0;
#pragma unroll
    for (int i = 0; i < 16; ++i) {
        if (i < per) {
            int c = c0 + i;
            int v = (c < nchunk) ? cnt[(long)c * MAXNB + b] : 0;
            vals[i] = v; lsum += v;
        }
    }
    int incl = lsum;
    for (int off = 1; off < 64; off <<= 1) {
        int o = __shfl_up(incl, off);
        if (lane >= off) incl += o;
    }
    int run = incl - lsum;
#pragma unroll
    for (int i = 0; i < 16; ++i) {
        if (i < per) {
            int c = c0 + i;
            if (c < nchunk) { cnt[(long)c * MAXNB + b] = run; run += vals[i]; }
        }
    }
    int tot = __shfl(incl, 63);
    if (lane == 0) btot[b] = tot;
}

// shared helper: 512-wide exclusive scan of btot into sbst[0..MAXNB], total at sbst[MAXNB]
__device__ inline void scan_btot(const int* __restrict__ btot, int* sbst, int t) {
    int v = btot[t];
    sbst[t] = v;
    __syncthreads();
    for (int off = 1; off < MAXNB; off <<= 1) {
        int tv = (t >= off) ? sbst[t - off] : 0;
        __syncthreads();
        sbst[t] += tv;
        __syncthreads();
    }
    int incl = sbst[t];
    __syncthreads();
    sbst[t] = incl - v;           // exclusive
    if (t == MAXNB - 1) sbst[MAXNB] = incl;
    __syncthreads();
}

// ---------------- 3. place edges (deterministic) ----------------
__global__ __launch_bounds__(512) void k_place(const int* __restrict__ src,
                                               const int* __restrict__ dst,
                                               const int* __restrict__ cnt,     // pref
                                               const int* __restrict__ btot,
                                               unsigned* __restrict__ pay, int n_edges) {
    __shared__ int sbst[MAXNB + 1];
    __shared__ int lcur[MAXNB];
    int t = threadIdx.x;
    scan_btot(btot, sbst, t);
    int c = blockIdx.x;
    int e0 = c * CHP, e1 = min(e0 + CHP, n_edges);
    for (int i = t; i < MAXNB; i += 512) lcur[i] = 0;
    __syncthreads();
    const int* pref = &cnt[(long)c * MAXNB];
    for (int e = e0 + t; e < e1; e += 512) {
        int d = dst[e];
        int b = d >> 8;
        int rank = atomicAdd(&lcur[b], 1);
        int pos = sbst[b] + pref[b] + rank;
        pay[pos] = ((unsigned)src[e] << 8) | (unsigned)(d & 255);
    }
}

// ---------------- 4. per-bucket exact CSR ----------------
__global__ __launch_bounds__(512) void k_csr(const unsigned* __restrict__ pay,
                                             const int* __restrict__ btot,
                                             int* __restrict__ row_start,
                                             int* __restrict__ csr,
                                             int num_dst, int n_edges, int nb) {
    __shared__ int sbst[MAXNB + 1];
    __shared__ int hist[BROWS];
    __shared__ int scn[BROWS];
    int t = threadIdx.x;
    scan_btot(btot, sbst, t);
    int b = blockIdx.x;
    int s0 = sbst[b], s1 = sbst[b + 1];
    if (t < BROWS) hist[t] = 0;
    __syncthreads();
    for (int i = s0 + t; i < s1; i += 512) atomicAdd(&hist[pay[i] & 255], 1);
    __syncthreads();
    int v = 0;
    if (t < BROWS) { v = hist[t]; scn[t] = v; }
    __syncthreads();
    for (int off = 1; off < BROWS; off <<= 1) {
        int tv = 0;
        if (t < BROWS && t >= off) tv = scn[t - off];
        __syncthreads();
        if (t < BROWS) scn[t] += tv;
        __syncthreads();
    }
    int r0 = b * BROWS;
    if (t < BROWS) {
        int excl = scn[t] - v;
        if (r0 + t < num_dst) row_start[r0 + t] = s0 + excl;
        hist[t] = excl;   // reuse as cursor
    }
    if (b == nb - 1 && t == 0) row_start[num_dst] = n_edges;
    __syncthreads();
    for (int i = s0 + t; i < s1; i += 512) {
        unsigned p = pay[i];
        int pos = atomicAdd(&hist[p & 255], 1);
        csr[s0 + pos] = (int)(p >> 8);
    }
}

// ---------------- 5. aggregate: wave per row, 8 lanes/edge, 16B loads ----------------
__global__ __launch_bounds__(256) void k_aggregate(const unsigned short* __restrict__ xb,
                                                   const int* __restrict__ row_start,
                                                   const int* __restrict__ csr,
                                                   unsigned short* __restrict__ hb, int num_dst) {
    int lane = threadIdx.x & 63;
    int r = (blockIdx.x * 256 + threadIdx.x) >> 6;
    if (r >= num_dst) return;
    int g = lane >> 3;          // edge slot within group of 8 (0..7)
    int c8 = (lane & 7) * 8;    // feature octet
    int s0 = row_start[r], s1 = row_start[r + 1];
    int rem = s1 - s0;
    float accA[8] = {0.f, 0.f, 0.f, 0.f, 0.f, 0.f, 0.f, 0.f};
    float accB[8] = {0.f, 0.f, 0.f, 0.f, 0.f, 0.f, 0.f, 0.f};
    for (int base = 0; base < rem; base += 64) {
        int sid = (base + lane < rem) ? csr[s0 + base + lane] : 0;
        int n = min(64, rem - base);
        int i = 0;
        for (; i + 15 < n; i += 16) {    // 2 gathers in flight
            int e0 = __shfl(sid, i + g);
            int e1 = __shfl(sid, i + 8 + g);
            short8 u0 = *(const short8*)&xb[(long)e0 * F + c8];
            short8 u1 = *(const short8*)&xb[(long)e1 * F + c8];
#pragma unroll
            for (int j = 0; j < 8; ++j) {
                accA[j] += bf2f((unsigned short)u0[j]);
                accB[j] += bf2f((unsigned short)u1[j]);
            }
        }
        for (; i < n; i += 8) {
            int eslot = i + g;
            int e = __shfl(sid, eslot);
            if (eslot < n) {
                short8 u = *(const short8*)&xb[(long)e * F + c8];
#pragma unroll
                for (int j = 0; j < 8; ++j) accA[j] += bf2f((unsigned short)u[j]);
            }
        }
    }
    float acc[8];
#pragma unroll
    for (int j = 0; j < 8; ++j) {
        acc[j] = accA[j] + accB[j];
        acc[j] += __shfl_xor(acc[j], 8);
        acc[j] += __shfl_xor(acc[j], 16);
        acc[j] += __shfl_xor(acc[j], 32);
    }
    if (lane < 8) {
        float inv = 1.0f / fmaxf((float)rem, 1.0f);
        short8 o;
#pragma unroll
        for (int j = 0; j < 8; ++j) o[j] = (short)f2bf(acc[j] * inv);
        *(short8*)&hb[(long)r * F + lane * 8] = o;
    }
}

// ---------------- 6. fused dual-GEMM, bf16 MFMA ----------------
__global__ __launch_bounds__(256) void k_gemm_mfma(
    const unsigned short* __restrict__ xb, const unsigned short* __restrict__ hb,
    const unsigned short* __restrict__ WtG,   // [n][k=0..127] bf16, pre-transposed
    const float* __restrict__ b, float* __restrict__ out, int num_dst)
{
    __shared__ __align__(16) unsigned short Atile[64 * LDK];
    __shared__ __align__(16) unsigned short Wt[64 * LDK];
    int t = threadIdx.x;
    int row0 = blockIdx.x * 64;

    for (int i = t; i < 64 * 16; i += 256) {
        int r = i >> 4, s = i & 15;
        *(short8*)&Wt[r * LDK + s * 8] = *(const short8*)&WtG[r * 128 + s * 8];
        int g = row0 + r;
        short8 v = {0, 0, 0, 0, 0, 0, 0, 0};
        if (g < num_dst)
            v = (s < 8) ? *(const short8*)&xb[(long)g * F + s * 8]
                        : *(const short8*)&hb[(long)g * F + (s - 8) * 8];
        *(short8*)&Atile[r * LDK + s * 8] = v;
    }
    __syncthreads();

    int lane = t & 63;
    int wave = t >> 6;
    int m = lane & 15;
    int quad = lane >> 4;
    const unsigned short* arow = &Atile[(wave * 16 + m) * LDK + quad * 8];

    float4v acc[4];
#pragma unroll
    for (int nt = 0; nt < 4; ++nt) acc[nt] = (float4v){0.f, 0.f, 0.f, 0.f};

#pragma unroll
    for (int kb = 0; kb < 4; ++kb) {
        short8 a = *(const short8*)(arow + kb * 32);
#pragma unroll
        for (int nt = 0; nt < 4; ++nt) {
            short8 bf = *(const short8*)&Wt[(nt * 16 + m) * LDK + quad * 8 + kb * 32];
            acc[nt] = __builtin_amdgcn_mfma_f32_16x16x32_bf16(a, bf, acc[nt], 0, 0, 0);
        }
    }

    int gr_base = row0 + wave * 16 + quad * 4;
#pragma unroll
    for (int nt = 0; nt < 4; ++nt) {
        int col = nt * 16 + m;
        float bias = b[col];
#pragma unroll
        for (int rg = 0; rg < 4; ++rg) {
            int g = gr_base + rg;
            if (g < num_dst) out[(long)g * F + col] = fmaxf(acc[nt][rg] + bias, 0.0f);
        }
    }
}

// ---------------- fallback (R0, proven) ----------------
__global__ __launch_bounds__(256) void k_scatter(const float* __restrict__ x, const int* __restrict__ src,
                                                 const int* __restrict__ dst, float* __restrict__ summed,
                                                 float* __restrict__ degf, int n_edges) {
    long tid = (long)blockIdx.x * 256 + threadIdx.x;
    int e = (int)(tid >> 6);
    if (e >= n_edges) return;
    int f = threadIdx.x & 63;
    atomicAdd(&summed[(long)dst[e] * F + f], x[(long)src[e] * F + f]);
    if (f == 0) atomicAdd(&degf[dst[e]], 1.0f);
}

__global__ __launch_bounds__(256) void k_gemm_shfl(
    const float* __restrict__ x, const float* __restrict__ Ws, const float* __restrict__ Wn,
    const float* __restrict__ b, const float* __restrict__ degf, float* inout, int num_dst)
{
    __shared__ float Wl[2 * F * F];
    for (int i = threadIdx.x; i < F * F; i += 256) { Wl[i] = Ws[i]; Wl[F * F + i] = Wn[i]; }
    __syncthreads();
    int lane = threadIdx.x & 63;
    int r = (blockIdx.x * 256 + threadIdx.x) >> 6;
    if (r >= num_dst) return;
    float xv = x[(long)r * F + lane];
    float hv = inout[(long)r * F + lane] / fmaxf(degf[r], 1.0f);
    float acc = b[lane];
#pragma unroll
    for (int k = 0; k < F; ++k) {
        acc += __shfl(xv, k) * Wl[k * F + lane];
        acc += __shfl(hv, k) * Wl[(F + k) * F + lane];
    }
    inout[(long)r * F + lane] = fmaxf(acc, 0.0f);
}

// ---------------- launch ----------------
extern "C" void kernel_launch(void* const* d_in, const int* in_sizes, int n_in,
                              void* d_out, int out_size, void* d_ws, size_t ws_size,
                              hipStream_t stream) {
    const float* x  = (const float*)d_in[0];
    const float* Ws = (const float*)d_in[1];
    const float* Wn = (const float*)d_in[2];
    const float* b  = (const float*)d_in[3];
    const int* src  = (const int*)d_in[4];
    const int* dst  = (const int*)d_in[5];
    int n_edges = in_sizes[4];
    int num_dst = out_size / F;
    float* out = (float*)d_out;

    int nchunk = (n_edges + CHP - 1) / CHP;
    int nb = (num_dst + BROWS - 1) / BROWS;

    char* ws = (char*)d_ws;
    size_t off = 0;
    auto alloc = [&](size_t bytes) { char* p = ws + off; off = (off + bytes + 255) & ~(size_t)255; return p; };
    unsigned short* xb  = (unsigned short*)alloc((size_t)num_dst * F * 2);
    unsigned short* hb  = (unsigned short*)alloc((size_t)num_dst * F * 2);
    unsigned* pay       = (unsigned*)alloc((size_t)n_edges * 4);
    int* csr            = (int*)alloc((size_t)n_edges * 4);
    int* row_start      = (int*)alloc((size_t)(num_dst + 1) * 4);
    unsigned short* WtG = (unsigned short*)alloc(2 * F * F * 2);
    int* cnt            = (int*)alloc((size_t)nchunk * MAXNB * 4);
    int* btot           = (int*)alloc(MAXNB * 4);
    bool big_ws = (off <= ws_size) && (nb <= MAXNB) && (nchunk <= 1024);

    if (big_ws) {
        long n4 = (long)num_dst * F / 4;
        int convgrid = max(2048, nchunk);
        k_conv<<<convgrid, 256, 0, stream>>>(x, Ws, Wn, xb, WtG, dst, cnt, n4, n_edges, nchunk);
        k_scanA<<<(MAXNB * 64 + 511) / 512, 512, 0, stream>>>(cnt, btot, nchunk);
        k_place<<<nchunk, 512, 0, stream>>>(src, dst, cnt, btot, pay, n_edges);
        k_csr<<<nb, 512, 0, stream>>>(pay, btot, row_start, csr, num_dst, n_edges, nb);
        k_aggregate<<<(num_dst + 3) / 4, 256, 0, stream>>>(xb, row_start, csr, hb, num_dst);
        k_gemm_mfma<<<(num_dst + 63) / 64, 256, 0, stream>>>(xb, hb, WtG, b, out, num_dst);
    } else {
        float* degf = (float*)d_ws;
        (void)hipMemsetAsync(d_out, 0, (size_t)out_size * sizeof(float), stream);
        (void)hipMemsetAsync(degf, 0, (size_t)num_dst * sizeof(float), stream);
        long tt = (long)n_edges * 64;
        k_scatter<<<(int)((tt + 255) / 256), 256, 0, stream>>>(x, src, dst, out, degf, n_edges);
        k_gemm_shfl<<<(num_dst + 3) / 4, 256, 0, stream>>>(x, Ws, Wn, b, degf, out, num_dst);
    }
}

// Round 13
// 164.498 us; speedup vs baseline: 1.1663x; 1.0156x over previous
//
#include <hip/hip_runtime.h>

// SAGE layer: out = relu(x @ W_self + (segment_sum(x[src], dst)/max(deg,1)) @ W_neigh + b)
//
// R13 = R12 with dual-row-per-wave aggregate (2x memory-level parallelism).
// Failed-experiment log (do not repeat):
//   R4: LDS float atomicAdd = CAS loops -> 448us.  R6: 1-block serial scan -> 121us.
//   R8: gather fused into GEMM blocks (TLP/16) -> 70us kernel.
//   R10: per-block O(c) serial prefix + fixed-stride regions -> k_place 44.5us.
//   R11: wider (16B) gather loads, same MLP -> neutral.
// Pipeline (6 dispatches, zero global atomics, no memsets on main path):
//   1. k_conv   2. k_scanA   3. k_place   4. k_csr
//   5. k_aggregate: wave per 2 rows; 8 lanes/edge 16B gathers interleaved across rows
//   6. k_gemm_mfma
// Fallback (small ws): R0 scatter + shfl gemm.

constexpr int F = 64;
constexpr int BROWS = 256;   // dst rows per bucket
constexpr int MAXNB = 512;   // max buckets (num_dst <= 131072)
constexpr int CHP = 4096;    // edges per chunk
constexpr int LDK = 136;     // 128 + 8 pad (bf16 elems)

typedef __attribute__((ext_vector_type(8))) short short8;
typedef __attribute__((ext_vector_type(4))) float float4v;

__device__ inline unsigned short f2bf(float f) {
    union { float f; unsigned u; } c; c.f = f;
    unsigned u = c.u;
    return (unsigned short)((u + 0x7FFFu + ((u >> 16) & 1u)) >> 16);  // RNE
}
__device__ inline float bf2f(unsigned short h) {
    union { unsigned u; float f; } c; c.u = (unsigned)h << 16;
    return c.f;
}

// ---------------- 1. x->bf16 + W->bf16^T + per-chunk bucket counts ----------------
__global__ __launch_bounds__(256) void k_conv(const float* __restrict__ x,
                                              const float* __restrict__ Ws,
                                              const float* __restrict__ Wn,
                                              unsigned short* __restrict__ xb,
                                              unsigned short* __restrict__ WtG,
                                              const int* __restrict__ dst,
                                              int* __restrict__ cnt,
                                              long n4, int n_edges, int nchunk) {
    __shared__ int hist[MAXNB];
    int t = threadIdx.x;
    long tid = (long)blockIdx.x * 256 + t;
    // W -> bf16 transposed
    if (tid < 2 * F * F) {
        int i = (int)tid;
        int n = i & 63, k = i >> 6;
        float v = (k < 64) ? Ws[k * 64 + n] : Wn[(k - 64) * 64 + n];
        WtG[n * 128 + k] = f2bf(v);
    }
    // chunk histogram (blocks < nchunk)
    int c = blockIdx.x;
    if (c < nchunk) {
        for (int i = t; i < MAXNB; i += 256) hist[i] = 0;
        __syncthreads();
        int e0 = c * CHP, e1 = min(e0 + CHP, n_edges);
        for (int e = e0 + t; e < e1; e += 256) atomicAdd(&hist[dst[e] >> 8], 1);
        __syncthreads();
        for (int i = t; i < MAXNB; i += 256) cnt[(long)c * MAXNB + i] = hist[i];
    }
    // x -> bf16
    for (long i = tid; i < n4; i += (long)gridDim.x * 256) {
        float4 v = ((const float4*)x)[i];
        ushort4 o;
        o.x = f2bf(v.x); o.y = f2bf(v.y); o.z = f2bf(v.z); o.w = f2bf(v.w);
        ((ushort4*)xb)[i] = o;
    }
}

// ---------------- 2. parallel column scan: wave per bucket ----------------
__global__ __launch_bounds__(512) void k_scanA(int* __restrict__ cnt,   // in-place -> pref
                                               int* __restrict__ btot, int nchunk) {
    int b = (blockIdx.x * 512 + threadIdx.x) >> 6;   // bucket = global wave id
    int lane = threadIdx.x & 63;
    if (b >= MAXNB) return;
    int per = (nchunk + 63) / 64;                    // chunks per lane (<=16 for nchunk<=1024)
    int c0 = lane * per;
    int vals[16];
    int lsum = 0;
#pragma unroll
    for (int i = 0; i < 16; ++i) {
        if (i < per) {
            int c = c0 + i;
            int v = (c < nchunk) ? cnt[(long)c * MAXNB + b] : 0;
            vals[i] = v; lsum += v;
        }
    }
    int incl = lsum;
    for (int off = 1; off < 64; off <<= 1) {
        int o = __shfl_up(incl, off);
        if (lane >= off) incl += o;
    }
    int run = incl - lsum;
#pragma unroll
    for (int i = 0; i < 16; ++i) {
        if (i < per) {
            int c = c0 + i;
            if (c < nchunk) { cnt[(long)c * MAXNB + b] = run; run += vals[i]; }
        }
    }
    int tot = __shfl(incl, 63);
    if (lane == 0) btot[b] = tot;
}

// shared helper: 512-wide exclusive scan of btot into sbst[0..MAXNB], total at sbst[MAXNB]
__device__ inline void scan_btot(const int* __restrict__ btot, int* sbst, int t) {
    int v = btot[t];
    sbst[t] = v;
    __syncthreads();
    for (int off = 1; off < MAXNB; off <<= 1) {
        int tv = (t >= off) ? sbst[t - off] : 0;
        __syncthreads();
        sbst[t] += tv;
        __syncthreads();
    }
    int incl = sbst[t];
    __syncthreads();
    sbst[t] = incl - v;           // exclusive
    if (t == MAXNB - 1) sbst[MAXNB] = incl;
    __syncthreads();
}

// ---------------- 3. place edges (deterministic) ----------------
__global__ __launch_bounds__(512) void k_place(const int* __restrict__ src,
                                               const int* __restrict__ dst,
                                               const int* __restrict__ cnt,     // pref
                                               const int* __restrict__ btot,
                                               unsigned* __restrict__ pay, int n_edges) {
    __shared__ int sbst[MAXNB + 1];
    __shared__ int lcur[MAXNB];
    int t = threadIdx.x;
    scan_btot(btot, sbst, t);
    int c = blockIdx.x;
    int e0 = c * CHP, e1 = min(e0 + CHP, n_edges);
    for (int i = t; i < MAXNB; i += 512) lcur[i] = 0;
    __syncthreads();
    const int* pref = &cnt[(long)c * MAXNB];
    for (int e = e0 + t; e < e1; e += 512) {
        int d = dst[e];
        int b = d >> 8;
        int rank = atomicAdd(&lcur[b], 1);
        int pos = sbst[b] + pref[b] + rank;
        pay[pos] = ((unsigned)src[e] << 8) | (unsigned)(d & 255);
    }
}

// ---------------- 4. per-bucket exact CSR ----------------
__global__ __launch_bounds__(512) void k_csr(const unsigned* __restrict__ pay,
                                             const int* __restrict__ btot,
                                             int* __restrict__ row_start,
                                             int* __restrict__ csr,
                                             int num_dst, int n_edges, int nb) {
    __shared__ int sbst[MAXNB + 1];
    __shared__ int hist[BROWS];
    __shared__ int scn[BROWS];
    int t = threadIdx.x;
    scan_btot(btot, sbst, t);
    int b = blockIdx.x;
    int s0 = sbst[b], s1 = sbst[b + 1];
    if (t < BROWS) hist[t] = 0;
    __syncthreads();
    for (int i = s0 + t; i < s1; i += 512) atomicAdd(&hist[pay[i] & 255], 1);
    __syncthreads();
    int v = 0;
    if (t < BROWS) { v = hist[t]; scn[t] = v; }
    __syncthreads();
    for (int off = 1; off < BROWS; off <<= 1) {
        int tv = 0;
        if (t < BROWS && t >= off) tv = scn[t - off];
        __syncthreads();
        if (t < BROWS) scn[t] += tv;
        __syncthreads();
    }
    int r0 = b * BROWS;
    if (t < BROWS) {
        int excl = scn[t] - v;
        if (r0 + t < num_dst) row_start[r0 + t] = s0 + excl;
        hist[t] = excl;   // reuse as cursor
    }
    if (b == nb - 1 && t == 0) row_start[num_dst] = n_edges;
    __syncthreads();
    for (int i = s0 + t; i < s1; i += 512) {
        unsigned p = pay[i];
        int pos = atomicAdd(&hist[p & 255], 1);
        csr[s0 + pos] = (int)(p >> 8);
    }
}

// ---------------- 5. aggregate: wave per 2 rows, interleaved 16B gathers ----------------
__global__ __launch_bounds__(256) void k_aggregate(const unsigned short* __restrict__ xb,
                                                   const int* __restrict__ row_start,
                                                   const int* __restrict__ csr,
                                                   unsigned short* __restrict__ hb, int num_dst) {
    int lane = threadIdx.x & 63;
    int w = (blockIdx.x * 256 + threadIdx.x) >> 6;   // global wave id
    int r0 = 2 * w, r1 = 2 * w + 1;
    if (r0 >= num_dst) return;
    int g = lane >> 3;          // edge slot within group of 8 (0..7)
    int c8 = (lane & 7) * 8;    // feature octet
    int sa = row_start[r0];
    int rema = row_start[r0 + 1] - sa;
    int sb = 0, remb = 0;
    if (r1 < num_dst) { sb = row_start[r1]; remb = row_start[r1 + 1] - sb; }
    float accA[8] = {0.f, 0.f, 0.f, 0.f, 0.f, 0.f, 0.f, 0.f};
    float accB[8] = {0.f, 0.f, 0.f, 0.f, 0.f, 0.f, 0.f, 0.f};
    int maxrem = max(rema, remb);
    for (int base = 0; base < maxrem; base += 64) {
        int nA = min(64, rema - base);   // may be <= 0
        int nB = min(64, remb - base);
        int sidA = (base + lane < rema) ? csr[sa + base + lane] : 0;
        int sidB = (base + lane < remb) ? csr[sb + base + lane] : 0;
        for (int i = 0; i < 64; i += 8) {
            if (i >= nA && i >= nB) break;
            int ea = __shfl(sidA, i + g);
            int eb = __shfl(sidB, i + g);
            if (i + g < nA) {
                short8 u = *(const short8*)&xb[(long)ea * F + c8];
#pragma unroll
                for (int j = 0; j < 8; ++j) accA[j] += bf2f((unsigned short)u[j]);
            }
            if (i + g < nB) {
                short8 u = *(const short8*)&xb[(long)eb * F + c8];
#pragma unroll
                for (int j = 0; j < 8; ++j) accB[j] += bf2f((unsigned short)u[j]);
            }
        }
    }
#pragma unroll
    for (int j = 0; j < 8; ++j) {
        accA[j] += __shfl_xor(accA[j], 8);
        accA[j] += __shfl_xor(accA[j], 16);
        accA[j] += __shfl_xor(accA[j], 32);
        accB[j] += __shfl_xor(accB[j], 8);
        accB[j] += __shfl_xor(accB[j], 16);
        accB[j] += __shfl_xor(accB[j], 32);
    }
    if (lane < 8) {
        float inv = 1.0f / fmaxf((float)rema, 1.0f);
        short8 o;
#pragma unroll
        for (int j = 0; j < 8; ++j) o[j] = (short)f2bf(accA[j] * inv);
        *(short8*)&hb[(long)r0 * F + lane * 8] = o;
    } else if (lane < 16 && r1 < num_dst) {
        float inv = 1.0f / fmaxf((float)remb, 1.0f);
        short8 o;
#pragma unroll
        for (int j = 0; j < 8; ++j) o[j] = (short)f2bf(accB[j] * inv);
        *(short8*)&hb[(long)r1 * F + (lane - 8) * 8] = o;
    }
}

// ---------------- 6. fused dual-GEMM, bf16 MFMA ----------------
__global__ __launch_bounds__(256) void k_gemm_mfma(
    const unsigned short* __restrict__ xb, const unsigned short* __restrict__ hb,
    const unsigned short* __restrict__ WtG,   // [n][k=0..127] bf16, pre-transposed
    const float* __restrict__ b, float* __restrict__ out, int num_dst)
{
    __shared__ __align__(16) unsigned short Atile[64 * LDK];
    __shared__ __align__(16) unsigned short Wt[64 * LDK];
    int t = threadIdx.x;
    int row0 = blockIdx.x * 64;

    for (int i = t; i < 64 * 16; i += 256) {
        int r = i >> 4, s = i & 15;
        *(short8*)&Wt[r * LDK + s * 8] = *(const short8*)&WtG[r * 128 + s * 8];
        int g = row0 + r;
        short8 v = {0, 0, 0, 0, 0, 0, 0, 0};
        if (g < num_dst)
            v = (s < 8) ? *(const short8*)&xb[(long)g * F + s * 8]
                        : *(const short8*)&hb[(long)g * F + (s - 8) * 8];
        *(short8*)&Atile[r * LDK + s * 8] = v;
    }
    __syncthreads();

    int lane = t & 63;
    int wave = t >> 6;
    int m = lane & 15;
    int quad = lane >> 4;
    const unsigned short* arow = &Atile[(wave * 16 + m) * LDK + quad * 8];

    float4v acc[4];
#pragma unroll
    for (int nt = 0; nt < 4; ++nt) acc[nt] = (float4v){0.f, 0.f, 0.f, 0.f};

#pragma unroll
    for (int kb = 0; kb < 4; ++kb) {
        short8 a = *(const short8*)(arow + kb * 32);
#pragma unroll
        for (int nt = 0; nt < 4; ++nt) {
            short8 bf = *(const short8*)&Wt[(nt * 16 + m) * LDK + quad * 8 + kb * 32];
            acc[nt] = __builtin_amdgcn_mfma_f32_16x16x32_bf16(a, bf, acc[nt], 0, 0, 0);
        }
    }

    int gr_base = row0 + wave * 16 + quad * 4;
#pragma unroll
    for (int nt = 0; nt < 4; ++nt) {
        int col = nt * 16 + m;
        float bias = b[col];
#pragma unroll
        for (int rg = 0; rg < 4; ++rg) {
            int g = gr_base + rg;
            if (g < num_dst) out[(long)g * F + col] = fmaxf(acc[nt][rg] + bias, 0.0f);
        }
    }
}

// ---------------- fallback (R0, proven) ----------------
__global__ __launch_bounds__(256) void k_scatter(const float* __restrict__ x, const int* __restrict__ src,
                                                 const int* __restrict__ dst, float* __restrict__ summed,
                                                 float* __restrict__ degf, int n_edges) {
    long tid = (long)blockIdx.x * 256 + threadIdx.x;
    int e = (int)(tid >> 6);
    if (e >= n_edges) return;
    int f = threadIdx.x & 63;
    atomicAdd(&summed[(long)dst[e] * F + f], x[(long)src[e] * F + f]);
    if (f == 0) atomicAdd(&degf[dst[e]], 1.0f);
}

__global__ __launch_bounds__(256) void k_gemm_shfl(
    const float* __restrict__ x, const float* __restrict__ Ws, const float* __restrict__ Wn,
    const float* __restrict__ b, const float* __restrict__ degf, float* inout, int num_dst)
{
    __shared__ float Wl[2 * F * F];
    for (int i = threadIdx.x; i < F * F; i += 256) { Wl[i] = Ws[i]; Wl[F * F + i] = Wn[i]; }
    __syncthreads();
    int lane = threadIdx.x & 63;
    int r = (blockIdx.x * 256 + threadIdx.x) >> 6;
    if (r >= num_dst) return;
    float xv = x[(long)r * F + lane];
    float hv = inout[(long)r * F + lane] / fmaxf(degf[r], 1.0f);
    float acc = b[lane];
#pragma unroll
    for (int k = 0; k < F; ++k) {
        acc += __shfl(xv, k) * Wl[k * F + lane];
        acc += __shfl(hv, k) * Wl[(F + k) * F + lane];
    }
    inout[(long)r * F + lane] = fmaxf(acc, 0.0f);
}

// ---------------- launch ----------------
extern "C" void kernel_launch(void* const* d_in, const int* in_sizes, int n_in,
                              void* d_out, int out_size, void* d_ws, size_t ws_size,
                              hipStream_t stream) {
    const float* x  = (const float*)d_in[0];
    const float* Ws = (const float*)d_in[1];
    const float* Wn = (const float*)d_in[2];
    const float* b  = (const float*)d_in[3];
    const int* src  = (const int*)d_in[4];
    const int* dst  = (const int*)d_in[5];
    int n_edges = in_sizes[4];
    int num_dst = out_size / F;
    float* out = (float*)d_out;

    int nchunk = (n_edges + CHP - 1) / CHP;
    int nb = (num_dst + BROWS - 1) / BROWS;

    char* ws = (char*)d_ws;
    size_t off = 0;
    auto alloc = [&](size_t bytes) { char* p = ws + off; off = (off + bytes + 255) & ~(size_t)255; return p; };
    unsigned short* xb  = (unsigned short*)alloc((size_t)num_dst * F * 2);
    unsigned short* hb  = (unsigned short*)alloc((size_t)num_dst * F * 2);
    unsigned* pay       = (unsigned*)alloc((size_t)n_edges * 4);
    int* csr            = (int*)alloc((size_t)n_edges * 4);
    int* row_start      = (int*)alloc((size_t)(num_dst + 1) * 4);
    unsigned short* WtG = (unsigned short*)alloc(2 * F * F * 2);
    int* cnt            = (int*)alloc((size_t)nchunk * MAXNB * 4);
    int* btot           = (int*)alloc(MAXNB * 4);
    bool big_ws = (off <= ws_size) && (nb <= MAXNB) && (nchunk <= 1024);

    if (big_ws) {
        long n4 = (long)num_dst * F / 4;
        int convgrid = max(2048, nchunk);
        k_conv<<<convgrid, 256, 0, stream>>>(x, Ws, Wn, xb, WtG, dst, cnt, n4, n_edges, nchunk);
        k_scanA<<<(MAXNB * 64 + 511) / 512, 512, 0, stream>>>(cnt, btot, nchunk);
        k_place<<<nchunk, 512, 0, stream>>>(src, dst, cnt, btot, pay, n_edges);
        k_csr<<<nb, 512, 0, stream>>>(pay, btot, row_start, csr, num_dst, n_edges, nb);
        int nwaves = (num_dst + 1) / 2;
        k_aggregate<<<(nwaves + 3) / 4, 256, 0, stream>>>(xb, row_start, csr, hb, num_dst);
        k_gemm_mfma<<<(num_dst + 63) / 64, 256, 0, stream>>>(xb, hb, WtG, b, out, num_dst);
    } else {
        float* degf = (float*)d_ws;
        (void)hipMemsetAsync(d_out, 0, (size_t)out_size * sizeof(float), stream);
        (void)hipMemsetAsync(degf, 0, (size_t)num_dst * sizeof(float), stream);
        long tt = (long)n_edges * 64;
        k_scatter<<<(int)((tt + 255) / 256), 256, 0, stream>>>(x, src, dst, out, degf, n_edges);
        k_gemm_shfl<<<(num_dst + 3) / 4, 256, 0, stream>>>(x, Ws, Wn, b, degf, out, num_dst);
    }
}